// Round 16
// baseline (147.492 us; speedup 1.0000x reference)
//
#include <hip/hip_runtime.h>
#include <stdint.h>

#define BB 16
#define CC 4
#define HH 768
#define WW 768
#define HW (HH * WW)          // 589824
#define NPIX (BB * HW)        // 9437184
#define NIMG (BB * (CC - 1))  // 48
#define BEST_STRIDE 16        // ull entries -> 128 B per (img,class)

// strip decomposition: one wave owns an 8-row x 64-col strip
#define SH 8
#define SW 64
#define SPIX (SH * SW)        // 512
#define SX (WW / SW)          // 12 strips across
#define SY (HH / SH)          // 96 strips down
#define SPI (SX * SY)         // 1152 strips per image
#define WPB 4                 // waves (strips) per block
#define CCL_TPB (WPB * 64)    // 256

typedef unsigned long long ull;

// ---------------- global union-find (border merges only) ----------------

__device__ __forceinline__ int find_root(int* P, int i) {
    int p = P[i];
    while (p != i) {
        int gp = P[p];
        P[i] = gp;   // path halving (benign race)
        i = p;
        p = gp;
    }
    return i;
}

__device__ __forceinline__ void merge(int* P, int a, int b) {
    a = find_root(P, a);
    b = find_root(P, b);
    while (a != b) {
        if (a < b) { int t = a; a = b; b = t; }  // a = larger root
        int old = atomicCAS(&P[a], a, b);        // attach larger under smaller
        if (old == a) return;
        a = find_root(P, old);
        b = find_root(P, b);
    }
}

// ---------------- LDS union-find (wave-private strip) ----------------

__device__ __forceinline__ int lfind(int* P, int i) {
    int p = P[i];
    while (p != i) {
        int gp = P[p];
        P[i] = gp;
        i = p;
        p = gp;
    }
    return i;
}

__device__ __forceinline__ void lmerge(int* P, int a, int b) {
    a = lfind(P, a);
    b = lfind(P, b);
    while (a != b) {
        if (a < b) { int t = a; a = b; b = t; }
        int old = atomicCAS(&P[a], a, b);
        if (old == a) return;
        a = lfind(P, old);
        b = lfind(P, b);
    }
}

__device__ __forceinline__ ull umax64(ull a, ull b) { return a > b ? a : b; }

// wait out this wave's outstanding LDS ops and pin the compiler scheduler
__device__ __forceinline__ void lds_fence() {
    asm volatile("s_waitcnt lgkmcnt(0)" ::: "memory");
    __builtin_amdgcn_sched_barrier(0);
}

// ---------------- kernels ----------------

// one WAVE per 8x64 strip, lane = column, labels in registers.
// phase A loads ALL 32 channel values before reducing (32 loads in flight).
// counts[pix] at local roots = (size<<2) | (class-1); 0 elsewhere.
__global__ __launch_bounds__(CCL_TPB) void k_strip_ccl(
        const float* __restrict__ pred,
        uint8_t* __restrict__ labels,
        int* __restrict__ parent,
        uint32_t* __restrict__ counts,
        ull* __restrict__ best) {
    __shared__ __align__(16) int sp_all[WPB][SPIX];   // 8 KB total

    if (blockIdx.x == 0) {
        for (int i = threadIdx.x; i < NIMG * BEST_STRIDE; i += CCL_TPB) best[i] = 0ull;
    }

    const int tid = (int)threadIdx.x;
    const int w = tid >> 6;
    const int lane = tid & 63;
    int* sp = sp_all[w];

    const int gs = blockIdx.x * WPB + w;    // global strip id
    const int img = gs / SPI;
    const int s = gs % SPI;
    const int tr = (s / SX) * SH;           // strip top row
    const int tc = (s % SX) * SW;           // strip left col
    const float* pb = pred + (size_t)img * CC * HW;
    const int imgbase = img * HW;
    const int col0 = tr * WW + tc + lane;   // global offset of (row 0, my col)

    int lab[SH];   // per-row labels (registers; loops fully unrolled)
    int v[SH];     // per-row run-start value

    // phase A1: issue ALL channel loads (32 independent, back-to-back)
    float b0[SH], b1[SH], b2[SH], b3[SH];
    #pragma unroll
    for (int r = 0; r < SH; ++r) {
        int gi = col0 + r * WW;
        b0[r] = pb[gi];
        b1[r] = pb[gi + HW];
        b2[r] = pb[gi + 2 * HW];
        b3[r] = pb[gi + 3 * HW];
    }
    // phase A2: reduce + write labels
    #pragma unroll
    for (int r = 0; r < SH; ++r) {
        int l = 0;
        float bv = b0[r];
        if (b1[r] > bv) { bv = b1[r]; l = 1; }
        if (b2[r] > bv) { bv = b2[r]; l = 2; }
        if (b3[r] > bv) { bv = b3[r]; l = 3; }
        lab[r] = l;
        labels[imgbase + col0 + r * WW] = (uint8_t)l;
    }

    // phase B1: run detection, all-register; issue sp writes (independent)
    #pragma unroll
    for (int r = 0; r < SH; ++r) {
        int l = lab[r];
        int labL = __shfl_up(l, 1, 64);
        bool isStart = l && (lane == 0 || labL != l);
        ull mask = __ballot(isStart);
        int li = (r << 6) + lane;
        int vr = li;
        if (l) {
            ull mle = mask & (~0ull >> (63 - lane));
            vr = (r << 6) + (63 - __clzll(mle));
        }
        v[r] = vr;
        sp[li] = vr;
    }
    lds_fence();   // all sp entries visible to this wave

    // phase B2: ordered vertical merges (crack criterion); only lmerge hits LDS
    #pragma unroll
    for (int r = 1; r < SH; ++r) {
        int l = lab[r];
        int lU = lab[r - 1];
        int labL = __shfl_up(l, 1, 64);
        int labUL = __shfl_up(lU, 1, 64);
        if (l && lU == l) {
            if (lane == 0 || !(labL == l && labUL == l))
                lmerge(sp, v[r], v[r - 1]);
        }
    }
    lds_fence();

    // phase C: fused flatten + run-count (counts into sp high bits at roots)
    #pragma unroll
    for (int r = 0; r < SH; ++r) {
        int l = lab[r];
        int labL = __shfl_up(l, 1, 64);
        int labR = __shfl_down(l, 1, 64);
        bool isStart = l && (lane == 0 || labL != l);
        bool isEnd = l && (lane == 63 || labR != l);
        ull endmask = __ballot(isEnd);
        int li = (r << 6) + lane;
        if (l) {
            int p = sp[li] & 0xFFFF;
            if (p != li) {
                int q0 = sp[p] & 0xFFFF;
                while (q0 != p) { p = q0; q0 = sp[p] & 0xFFFF; }
                sp[li] = p;  // p is the root; clean (count-free) value
            }
            if (isStart) {
                ull mge = endmask & (~0ull << lane);
                int epos = __ffsll((long long)mge) - 1;
                int runlen = epos - lane + 1;
                atomicAdd((unsigned int*)&sp[p], (unsigned int)runlen << 16);
            }
        }
    }
    lds_fence();

    // phase D: per-row coalesced writes of parent & counts
    #pragma unroll
    for (int r = 0; r < SH; ++r) {
        int li = (r << 6) + lane;
        int gi = imgbase + col0 + r * WW;
        int sv = sp[li];
        int root = sv & 0xFFFF;
        int pv = -1;
        uint32_t cv = 0u;
        if (lab[r]) {
            pv = imgbase + (tr + (root >> 6)) * WW + tc + (root & 63);
            // pack class into counts low bits: (size<<2) | (class-1)
            cv = (root == li) ? ((((uint32_t)sv >> 16) << 2) | (uint32_t)(lab[r] - 1)) : 0u;
        }
        parent[gi] = pv;
        counts[gi] = cv;
    }
}

// merge across strip borders: vertical cuts every 64 cols, horizontal cuts
// every 8 rows.
#define VED ((SX - 1) * HH)          // 8448
#define HED ((SY - 1) * WW)          // 72960
#define EPI (VED + HED)              // 81408
__global__ void k_border_merge(const uint8_t* __restrict__ labels, int* parent) {
    int t = blockIdx.x * blockDim.x + threadIdx.x;
    if (t >= BB * EPI) return;
    int img = t / EPI;
    int e = t % EPI;
    int a, b;
    if (e < VED) {
        int j = e / HH, r = e % HH;
        int c = (j + 1) * SW - 1;
        a = r * WW + c;
        b = a + 1;
    } else {
        e -= VED;
        int j = e / WW, c = e % WW;
        int r = (j + 1) * SH - 1;
        a = r * WW + c;
        b = a + WW;
    }
    int ga = img * HW + a, gb = img * HW + b;
    uint8_t la = labels[ga];
    if (la && labels[gb] == la) merge(parent, ga, gb);
}

// fused compress + best:
// for each local root (counts>0): chase to global root, point parent at it,
// atomicAdd its packed count there; the returned prefix (old + add) equals the
// TRUE total for the serialization-last adder, so max over all reported
// prefixes and self-reports = max over true component sizes. Per-block LDS
// reduction (block = 1024 px inside one image), then 3 atomicMax per block.
#define CB_TPB 256
__global__ void k_compress_best(int* __restrict__ parent,
                                uint32_t* __restrict__ counts,
                                ull* __restrict__ best) {
    __shared__ ull sw[(CB_TPB / 64) * 3];
    int q = blockIdx.x * blockDim.x + threadIdx.x;
    ull l0 = 0, l1 = 0, l2 = 0;
    if (q < NPIX / 4) {
        int t = q * 4;
        uint4 cv = *(const uint4*)&counts[t];
        if (cv.x | cv.y | cv.z | cv.w) {
            uint32_t cs[4] = {cv.x, cv.y, cv.z, cv.w};
            #pragma unroll
            for (int j = 0; j < 4; ++j) {
                uint32_t raw = cs[j];
                if (!raw) continue;
                int i = t + j;
                int g = parent[i];
                uint32_t tot;   // packed (size<<2)|class prefix
                int gidx;
                if (g == i) {
                    tot = raw;            // self-report; later adds covered by adders
                    gidx = i;
                } else {
                    while (true) { int pg = parent[g]; if (pg == g) break; g = pg; }
                    parent[i] = g;
                    uint32_t old = atomicAdd(&counts[g], raw & ~3u);
                    tot = old + (raw & ~3u);  // prefix incl. my add; class bits from g
                    gidx = g;
                }
                int cls = (int)(tot & 3u);
                ull key = ((ull)(tot >> 2) << 32) | (ull)(~(uint32_t)gidx);
                if (cls == 0) l0 = umax64(l0, key);
                else if (cls == 1) l1 = umax64(l1, key);
                else l2 = umax64(l2, key);
            }
        }
    }
    // 64-lane butterfly per class
    #pragma unroll
    for (int m = 1; m < 64; m <<= 1) {
        l0 = umax64(l0, __shfl_xor(l0, m, 64));
        l1 = umax64(l1, __shfl_xor(l1, m, 64));
        l2 = umax64(l2, __shfl_xor(l2, m, 64));
    }
    int lane = threadIdx.x & 63;
    int wid = threadIdx.x >> 6;
    if (lane == 0) { sw[wid * 3 + 0] = l0; sw[wid * 3 + 1] = l1; sw[wid * 3 + 2] = l2; }
    __syncthreads();
    if (threadIdx.x < 3) {
        ull m = 0;
        for (int w = 0; w < CB_TPB / 64; ++w) m = umax64(m, sw[w * 3 + threadIdx.x]);
        if (m) {
            int img = (int)(((long long)blockIdx.x * CB_TPB * 4) / HW);  // block within one image
            atomicMax(&best[(img * 3 + (int)threadIdx.x) * BEST_STRIDE], m);
        }
    }
}

// final output: parent-only (no labels read). global root = parent[parent[t]];
// bg -> INT_MIN sentinel (matches no root; empty-class root is -1, fg roots >= 0).
__global__ void k_output(const int* __restrict__ parent,
                         const ull* __restrict__ best,
                         float* __restrict__ out) {
    int q = blockIdx.x * blockDim.x + threadIdx.x;
    if (q >= NPIX / 4) return;
    int t = q * 4;
    int b = t / HW;
    int i = t - b * HW;
    int4 pv = *(const int4*)&parent[t];
    int r0 = (int)(~(uint32_t)best[(b * 3 + 0) * BEST_STRIDE]);
    int r1 = (int)(~(uint32_t)best[(b * 3 + 1) * BEST_STRIDE]);
    int r2 = (int)(~(uint32_t)best[(b * 3 + 2) * BEST_STRIDE]);

    int ps[4] = {pv.x, pv.y, pv.z, pv.w};
    float4 o0, o1, o2, o3;
    float* c0 = &o0.x; float* c1 = &o1.x; float* c2 = &o2.x; float* c3 = &o3.x;
    #pragma unroll
    for (int j = 0; j < 4; ++j) {
        int g = (ps[j] >= 0) ? parent[ps[j]] : (int)0x80000000;  // strip-local -> cache hit
        float f1 = (g == r0) ? 1.0f : 0.0f;
        float f2 = (g == r1) ? 1.0f : 0.0f;
        float f3 = (g == r2) ? 1.0f : 0.0f;
        c1[j] = f1;
        c2[j] = f2;
        c3[j] = f3;
        c0[j] = 1.0f - f1 - f2 - f3;   // best roots are distinct pixels -> at most one hit
    }
    float* o = out + (size_t)b * CC * HW + i;
    *(float4*)&o[0] = o0;
    *(float4*)&o[HW] = o1;
    *(float4*)&o[2 * HW] = o2;
    *(float4*)&o[3 * HW] = o3;
}

// ---------------- launch ----------------

extern "C" void kernel_launch(void* const* d_in, const int* in_sizes, int n_in,
                              void* d_out, int out_size, void* d_ws, size_t ws_size,
                              hipStream_t stream) {
    const float* pred = (const float*)d_in[0];
    float* out = (float*)d_out;

    uint8_t* labels = (uint8_t*)d_ws;                            // NPIX bytes
    int* parent = (int*)((char*)d_ws + NPIX);                    // NPIX*4 bytes
    ull* best = (ull*)((char*)d_ws + NPIX + (size_t)NPIX * 4);   // NIMG*BEST_STRIDE*8
    uint32_t* counts = (uint32_t*)d_out;  // reuse d_out; overwritten by k_output

    const int TPB = 256;

    k_strip_ccl<<<BB * SPI / WPB, CCL_TPB, 0, stream>>>(pred, labels, parent, counts, best);
    k_border_merge<<<(BB * EPI + TPB - 1) / TPB, TPB, 0, stream>>>(labels, parent);
    k_compress_best<<<(NPIX / 4 + CB_TPB - 1) / CB_TPB, CB_TPB, 0, stream>>>(parent, counts, best);
    k_output<<<(NPIX / 4 + TPB - 1) / TPB, TPB, 0, stream>>>(parent, best, out);
}

// Round 17
// 143.842 us; speedup vs baseline: 1.0254x; 1.0254x over previous
//
#include <hip/hip_runtime.h>
#include <stdint.h>

#define BB 16
#define CC 4
#define HH 768
#define WW 768
#define HW (HH * WW)          // 589824
#define NPIX (BB * HW)        // 9437184
#define NIMG (BB * (CC - 1))  // 48
#define BEST_STRIDE 16        // ull entries -> 128 B per (img,class)

// strip decomposition: one wave owns an 8-row x 64-col strip
#define SH 8
#define SW 64
#define SPIX (SH * SW)        // 512
#define SX (WW / SW)          // 12 strips across
#define SY (HH / SH)          // 96 strips down
#define SPI (SX * SY)         // 1152 strips per image
#define WPB 4                 // waves (strips) per block
#define CCL_TPB (WPB * 64)    // 256

typedef unsigned long long ull;

// ---------------- global union-find (border merges only) ----------------

__device__ __forceinline__ int find_root(int* P, int i) {
    int p = P[i];
    while (p != i) {
        int gp = P[p];
        P[i] = gp;   // path halving (benign race)
        i = p;
        p = gp;
    }
    return i;
}

__device__ __forceinline__ void merge(int* P, int a, int b) {
    a = find_root(P, a);
    b = find_root(P, b);
    while (a != b) {
        if (a < b) { int t = a; a = b; b = t; }  // a = larger root
        int old = atomicCAS(&P[a], a, b);        // attach larger under smaller
        if (old == a) return;
        a = find_root(P, old);
        b = find_root(P, b);
    }
}

// ---------------- LDS union-find (wave-private strip) ----------------

__device__ __forceinline__ int lfind(int* P, int i) {
    int p = P[i];
    while (p != i) {
        int gp = P[p];
        P[i] = gp;
        i = p;
        p = gp;
    }
    return i;
}

__device__ __forceinline__ void lmerge(int* P, int a, int b) {
    a = lfind(P, a);
    b = lfind(P, b);
    while (a != b) {
        if (a < b) { int t = a; a = b; b = t; }
        int old = atomicCAS(&P[a], a, b);
        if (old == a) return;
        a = lfind(P, old);
        b = lfind(P, b);
    }
}

__device__ __forceinline__ ull umax64(ull a, ull b) { return a > b ? a : b; }

// wait out this wave's outstanding LDS ops and pin the compiler scheduler
__device__ __forceinline__ void lds_fence() {
    asm volatile("s_waitcnt lgkmcnt(0)" ::: "memory");
    __builtin_amdgcn_sched_barrier(0);
}

// ---------------- kernels ----------------

// one WAVE per 8x64 strip, lane = column, labels in registers.
// phase A loads ALL 32 channel values before reducing (32 loads in flight).
// counts[pix] at local roots = (size<<2) | (class-1); 0 elsewhere.
__global__ __launch_bounds__(CCL_TPB) void k_strip_ccl(
        const float* __restrict__ pred,
        uint8_t* __restrict__ labels,
        int* __restrict__ parent,
        uint32_t* __restrict__ counts,
        ull* __restrict__ best) {
    __shared__ __align__(16) int sp_all[WPB][SPIX];   // 8 KB total

    if (blockIdx.x == 0) {
        for (int i = threadIdx.x; i < NIMG * BEST_STRIDE; i += CCL_TPB) best[i] = 0ull;
    }

    const int tid = (int)threadIdx.x;
    const int w = tid >> 6;
    const int lane = tid & 63;
    int* sp = sp_all[w];

    const int gs = blockIdx.x * WPB + w;    // global strip id
    const int img = gs / SPI;
    const int s = gs % SPI;
    const int tr = (s / SX) * SH;           // strip top row
    const int tc = (s % SX) * SW;           // strip left col
    const float* pb = pred + (size_t)img * CC * HW;
    const int imgbase = img * HW;
    const int col0 = tr * WW + tc + lane;   // global offset of (row 0, my col)

    int lab[SH];   // per-row labels (registers; loops fully unrolled)
    int v[SH];     // per-row run-start value

    // phase A1: issue ALL channel loads (32 independent, back-to-back)
    float b0[SH], b1[SH], b2[SH], b3[SH];
    #pragma unroll
    for (int r = 0; r < SH; ++r) {
        int gi = col0 + r * WW;
        b0[r] = pb[gi];
        b1[r] = pb[gi + HW];
        b2[r] = pb[gi + 2 * HW];
        b3[r] = pb[gi + 3 * HW];
    }
    // phase A2: reduce + write labels
    #pragma unroll
    for (int r = 0; r < SH; ++r) {
        int l = 0;
        float bv = b0[r];
        if (b1[r] > bv) { bv = b1[r]; l = 1; }
        if (b2[r] > bv) { bv = b2[r]; l = 2; }
        if (b3[r] > bv) { bv = b3[r]; l = 3; }
        lab[r] = l;
        labels[imgbase + col0 + r * WW] = (uint8_t)l;
    }

    // phase B1: run detection, all-register; issue sp writes (independent)
    #pragma unroll
    for (int r = 0; r < SH; ++r) {
        int l = lab[r];
        int labL = __shfl_up(l, 1, 64);
        bool isStart = l && (lane == 0 || labL != l);
        ull mask = __ballot(isStart);
        int li = (r << 6) + lane;
        int vr = li;
        if (l) {
            ull mle = mask & (~0ull >> (63 - lane));
            vr = (r << 6) + (63 - __clzll(mle));
        }
        v[r] = vr;
        sp[li] = vr;
    }
    lds_fence();   // all sp entries visible to this wave

    // phase B2: ordered vertical merges (crack criterion); only lmerge hits LDS
    #pragma unroll
    for (int r = 1; r < SH; ++r) {
        int l = lab[r];
        int lU = lab[r - 1];
        int labL = __shfl_up(l, 1, 64);
        int labUL = __shfl_up(lU, 1, 64);
        if (l && lU == l) {
            if (lane == 0 || !(labL == l && labUL == l))
                lmerge(sp, v[r], v[r - 1]);
        }
    }
    lds_fence();

    // phase C: fused flatten + run-count (counts into sp high bits at roots)
    #pragma unroll
    for (int r = 0; r < SH; ++r) {
        int l = lab[r];
        int labL = __shfl_up(l, 1, 64);
        int labR = __shfl_down(l, 1, 64);
        bool isStart = l && (lane == 0 || labL != l);
        bool isEnd = l && (lane == 63 || labR != l);
        ull endmask = __ballot(isEnd);
        int li = (r << 6) + lane;
        if (l) {
            int p = sp[li] & 0xFFFF;
            if (p != li) {
                int q0 = sp[p] & 0xFFFF;
                while (q0 != p) { p = q0; q0 = sp[p] & 0xFFFF; }
                sp[li] = p;  // p is the root; clean (count-free) value
            }
            if (isStart) {
                ull mge = endmask & (~0ull << lane);
                int epos = __ffsll((long long)mge) - 1;
                int runlen = epos - lane + 1;
                atomicAdd((unsigned int*)&sp[p], (unsigned int)runlen << 16);
            }
        }
    }
    lds_fence();

    // phase D: per-row coalesced writes of parent & counts
    #pragma unroll
    for (int r = 0; r < SH; ++r) {
        int li = (r << 6) + lane;
        int gi = imgbase + col0 + r * WW;
        int sv = sp[li];
        int root = sv & 0xFFFF;
        int pv = -1;
        uint32_t cv = 0u;
        if (lab[r]) {
            pv = imgbase + (tr + (root >> 6)) * WW + tc + (root & 63);
            // pack class into counts low bits: (size<<2) | (class-1)
            cv = (root == li) ? ((((uint32_t)sv >> 16) << 2) | (uint32_t)(lab[r] - 1)) : 0u;
        }
        parent[gi] = pv;
        counts[gi] = cv;
    }
}

// merge across strip borders: vertical cuts every 64 cols, horizontal cuts
// every 8 rows.
#define VED ((SX - 1) * HH)          // 8448
#define HED ((SY - 1) * WW)          // 72960
#define EPI (VED + HED)              // 81408
__global__ void k_border_merge(const uint8_t* __restrict__ labels, int* parent) {
    int t = blockIdx.x * blockDim.x + threadIdx.x;
    if (t >= BB * EPI) return;
    int img = t / EPI;
    int e = t % EPI;
    int a, b;
    if (e < VED) {
        int j = e / HH, r = e % HH;
        int c = (j + 1) * SW - 1;
        a = r * WW + c;
        b = a + 1;
    } else {
        e -= VED;
        int j = e / WW, c = e % WW;
        int r = (j + 1) * SH - 1;
        a = r * WW + c;
        b = a + WW;
    }
    int ga = img * HW + a, gb = img * HW + b;
    uint8_t la = labels[ga];
    if (la && labels[gb] == la) merge(parent, ga, gb);
}

// for each local root (counts>0): chase to global root, point parent at it,
// move its packed count there (class bits of the target root are preserved
// because we add raw & ~3).
__global__ void k_compress(int* __restrict__ parent, uint32_t* __restrict__ counts) {
    int q = blockIdx.x * blockDim.x + threadIdx.x;
    if (q >= NPIX / 4) return;
    int t = q * 4;
    uint4 cv = *(const uint4*)&counts[t];
    if (!(cv.x | cv.y | cv.z | cv.w)) return;
    uint32_t cs[4] = {cv.x, cv.y, cv.z, cv.w};
    #pragma unroll
    for (int j = 0; j < 4; ++j) {
        if (!cs[j]) continue;
        int i = t + j;
        int g = parent[i];
        if (g == i) continue;   // already a global root
        while (true) { int pg = parent[g]; if (pg == g) break; g = pg; }
        parent[i] = g;
        atomicAdd(&counts[g], cs[j] & ~3u);
        counts[i] = 0;
    }
}

// per (img, class) max over global roots of key = (count<<32) | ~root_index
// class comes from counts low bits -> no labels read.
#define BEST_BLK_PER_IMG 144
#define BEST_TPB 256
#define BEST_PIX_PER_BLK (HW / BEST_BLK_PER_IMG)  // 4096
__global__ void k_best(const uint32_t* __restrict__ counts,
                       ull* __restrict__ best) {
    __shared__ ull sw[(BEST_TPB / 64) * 3];
    int img = blockIdx.x / BEST_BLK_PER_IMG;
    int chunk = blockIdx.x % BEST_BLK_PER_IMG;
    int base = img * HW + chunk * BEST_PIX_PER_BLK;

    ull l0 = 0, l1 = 0, l2 = 0;
    for (int k = 0; k < BEST_PIX_PER_BLK; k += BEST_TPB * 4) {
        int t = base + k + (int)threadIdx.x * 4;
        uint4 cv = *(const uint4*)&counts[t];
        if (cv.x | cv.y | cv.z | cv.w) {
            uint32_t cs[4] = {cv.x, cv.y, cv.z, cv.w};
            #pragma unroll
            for (int j = 0; j < 4; ++j) {
                uint32_t raw = cs[j];
                if (raw) {
                    int cc = (int)(raw & 3u);
                    ull key = ((ull)(raw >> 2) << 32) | (ull)(~(uint32_t)(t + j));
                    if (cc == 0) l0 = umax64(l0, key);
                    else if (cc == 1) l1 = umax64(l1, key);
                    else l2 = umax64(l2, key);
                }
            }
        }
    }
    #pragma unroll
    for (int m = 1; m < 64; m <<= 1) {
        l0 = umax64(l0, __shfl_xor(l0, m, 64));
        l1 = umax64(l1, __shfl_xor(l1, m, 64));
        l2 = umax64(l2, __shfl_xor(l2, m, 64));
    }
    int lane = threadIdx.x & 63;
    int wid = threadIdx.x >> 6;
    if (lane == 0) { sw[wid * 3 + 0] = l0; sw[wid * 3 + 1] = l1; sw[wid * 3 + 2] = l2; }
    __syncthreads();
    if (threadIdx.x < 3) {
        ull m = 0;
        for (int w = 0; w < BEST_TPB / 64; ++w) m = umax64(m, sw[w * 3 + threadIdx.x]);
        if (m) atomicMax(&best[(img * 3 + (int)threadIdx.x) * BEST_STRIDE], m);
    }
}

// final output: parent-only (no labels read). global root = parent[parent[t]];
// bg -> INT_MIN sentinel (matches no root; empty-class root is -1, fg roots >= 0).
__global__ void k_output(const int* __restrict__ parent,
                         const ull* __restrict__ best,
                         float* __restrict__ out) {
    int q = blockIdx.x * blockDim.x + threadIdx.x;
    if (q >= NPIX / 4) return;
    int t = q * 4;
    int b = t / HW;
    int i = t - b * HW;
    int4 pv = *(const int4*)&parent[t];
    int r0 = (int)(~(uint32_t)best[(b * 3 + 0) * BEST_STRIDE]);
    int r1 = (int)(~(uint32_t)best[(b * 3 + 1) * BEST_STRIDE]);
    int r2 = (int)(~(uint32_t)best[(b * 3 + 2) * BEST_STRIDE]);

    int ps[4] = {pv.x, pv.y, pv.z, pv.w};
    float4 o0, o1, o2, o3;
    float* c0 = &o0.x; float* c1 = &o1.x; float* c2 = &o2.x; float* c3 = &o3.x;
    #pragma unroll
    for (int j = 0; j < 4; ++j) {
        int g = (ps[j] >= 0) ? parent[ps[j]] : (int)0x80000000;  // strip-local -> cache hit
        float f1 = (g == r0) ? 1.0f : 0.0f;
        float f2 = (g == r1) ? 1.0f : 0.0f;
        float f3 = (g == r2) ? 1.0f : 0.0f;
        c1[j] = f1;
        c2[j] = f2;
        c3[j] = f3;
        c0[j] = 1.0f - f1 - f2 - f3;   // best roots are distinct pixels -> at most one hit
    }
    float* o = out + (size_t)b * CC * HW + i;
    *(float4*)&o[0] = o0;
    *(float4*)&o[HW] = o1;
    *(float4*)&o[2 * HW] = o2;
    *(float4*)&o[3 * HW] = o3;
}

// ---------------- launch ----------------

extern "C" void kernel_launch(void* const* d_in, const int* in_sizes, int n_in,
                              void* d_out, int out_size, void* d_ws, size_t ws_size,
                              hipStream_t stream) {
    const float* pred = (const float*)d_in[0];
    float* out = (float*)d_out;

    uint8_t* labels = (uint8_t*)d_ws;                            // NPIX bytes
    int* parent = (int*)((char*)d_ws + NPIX);                    // NPIX*4 bytes
    ull* best = (ull*)((char*)d_ws + NPIX + (size_t)NPIX * 4);   // NIMG*BEST_STRIDE*8
    uint32_t* counts = (uint32_t*)d_out;  // reuse d_out; overwritten by k_output

    const int TPB = 256;

    k_strip_ccl<<<BB * SPI / WPB, CCL_TPB, 0, stream>>>(pred, labels, parent, counts, best);
    k_border_merge<<<(BB * EPI + TPB - 1) / TPB, TPB, 0, stream>>>(labels, parent);
    k_compress<<<(NPIX / 4 + TPB - 1) / TPB, TPB, 0, stream>>>(parent, counts);
    k_best<<<BB * BEST_BLK_PER_IMG, BEST_TPB, 0, stream>>>(counts, best);
    k_output<<<(NPIX / 4 + TPB - 1) / TPB, TPB, 0, stream>>>(parent, best, out);
}